// Round 1
// 249.835 us; speedup vs baseline: 1.0667x; 1.0667x over previous
//
#include <hip/hip_runtime.h>

// AttentionLoRA: B=1, S=4096, D=1024, H=16, HD=64.
// Pipeline (4 kernels):
//   cvt_all (f32->bf16 + bias pack)
//   gemm1: QKV NT-GEMM, epilogue fuses RoPE (q/k) and V-transpose -> vT (h,hd,s)
//   flash: causal, exp2 softmax (no running max -> partial O,l are summable).
//          1024 blocks x 512 thr: each block = ONE q-tile (64 rows); wave-group 0
//          computes even kv tiles, group 1 odd kv tiles (zero barrier-idle waves),
//          partials merged once via LDS. P kept fully in-register via swapped
//          QK^T (mfma(K,Q)) + pk2t + permlane16/32_swap (no sP round trip).
//          qt = 63-(c>>4): heavy blocks dispatch first. h = c&15: 2 heads/XCD.
//   gemm2: out-proj, 128x64 tiles (512 blocks, 2/CU), f32 out.

#define S_LEN 4096
#define DIM   1024
#define NH    16
#define HD    64

typedef __attribute__((ext_vector_type(8))) short bf16x8;   // 8 bf16 = 4 VGPRs
typedef __attribute__((ext_vector_type(4))) float f32x4;

__device__ __forceinline__ unsigned short f2b(float f) {
  union { float f; unsigned int u; } v; v.f = f;
  unsigned int r = (v.u + 0x7fffu + ((v.u >> 16) & 1u)) >> 16;  // RNE
  return (unsigned short)r;
}
__device__ __forceinline__ float b2f(unsigned short h) {
  union { unsigned int u; float f; } v; v.u = ((unsigned int)h) << 16;
  return v.f;
}
// pack two f32 -> two bf16 by truncation (<=1ulp)
__device__ __forceinline__ unsigned int pk2t(float a, float b) {
  union { float f; unsigned int u; } x, y; x.f = a; y.f = b;
  return (x.u >> 16) | (y.u & 0xffff0000u);
}
__device__ __forceinline__ void gload16(const void* g, void* l) {
  __builtin_amdgcn_global_load_lds(
      (const __attribute__((address_space(1))) unsigned int*)g,
      (__attribute__((address_space(3))) unsigned int*)l, 16, 0, 0);
}
__device__ __forceinline__ f32x4 fzero4() { f32x4 z = {0.f, 0.f, 0.f, 0.f}; return z; }

// ---------------- fused f32->bf16 convert (x, wq, wk, wv, wo) + bias pack ----------
__global__ void cvt_all(const float* __restrict__ x, const float* __restrict__ wq,
                        const float* __restrict__ wk, const float* __restrict__ wv,
                        const float* __restrict__ wo, const float* __restrict__ qb,
                        const float* __restrict__ kb, const float* __restrict__ vbs,
                        const float* __restrict__ ob, unsigned short* __restrict__ xb,
                        unsigned short* __restrict__ wqkvb, unsigned short* __restrict__ wobb,
                        float* __restrict__ biasq, float* __restrict__ biaso) {
  int i = blockIdx.x * 256 + threadIdx.x;  // float4 index
  if (i < 2097152) {
    const float* src; unsigned short* dst; int off;
    if (i < 1048576)      { src = x;  dst = xb;              off = i; }
    else if (i < 1310720) { src = wq; dst = wqkvb;           off = i - 1048576; }
    else if (i < 1572864) { src = wk; dst = wqkvb + 1048576; off = i - 1310720; }
    else if (i < 1835008) { src = wv; dst = wqkvb + 2097152; off = i - 1572864; }
    else                  { src = wo; dst = wobb;            off = i - 1835008; }
    float4 v = ((const float4*)src)[off];
    unsigned int lo = (unsigned int)f2b(v.x) | ((unsigned int)f2b(v.y) << 16);
    unsigned int hi = (unsigned int)f2b(v.z) | ((unsigned int)f2b(v.w) << 16);
    ((uint2*)dst)[off] = make_uint2(lo, hi);
  } else if (i < 2097152 + 1024) {
    int j = i - 2097152;
    if (j < 256)      ((float4*)biasq)[j]              = ((const float4*)qb)[j];
    else if (j < 512) ((float4*)(biasq + 1024))[j-256] = ((const float4*)kb)[j-256];
    else if (j < 768) ((float4*)(biasq + 2048))[j-512] = ((const float4*)vbs)[j-512];
    else              ((float4*)biaso)[j-768]          = ((const float4*)ob)[j-768];
  }
}

// ---------------- gemm1: QKV NT-GEMM with fused RoPE + V-transpose epilogue -------
// 128x128 tile, BK=32, 4 waves each 64x64. Ping-pong LDS staging, 1 barrier/K-iter.
__global__ __launch_bounds__(256) void gemm_qkv(
    const unsigned short* __restrict__ A, const unsigned short* __restrict__ B,
    const float* __restrict__ bias, unsigned short* __restrict__ dq,
    unsigned short* __restrict__ dk, unsigned short* __restrict__ vtout,
    const float* __restrict__ fc, const float* __restrict__ fs, int K) {
  __shared__ alignas(16) unsigned short sA[2][128 * 32];
  __shared__ alignas(16) unsigned short sB[2][128 * 32];
  const int tid = threadIdx.x;
  const int lane = tid & 63, wave = tid >> 6;
  const int ln = lane & 15, quad = lane >> 4;
  const int bm = blockIdx.x * 128, bn = blockIdx.y * 128;
  const int wr = (wave >> 1) * 64, wc = (wave & 1) * 64;

  f32x4 acc[4][4];
#pragma unroll
  for (int i = 0; i < 4; ++i)
#pragma unroll
    for (int j = 0; j < 4; ++j) acc[i][j] = fzero4();

#pragma unroll
  for (int i = 0; i < 2; ++i) {
    int o = (i * 256 + tid) * 16;
    int e = o >> 1;
    int row = e >> 5, col = e & 31;
    gload16(A + (size_t)(bm + row) * K + col, (char*)sA[0] + o);
    gload16(B + (size_t)(bn + row) * K + col, (char*)sB[0] + o);
  }

  int buf = 0;
  for (int k0 = 0; k0 < K; k0 += 32, buf ^= 1) {
    __syncthreads();
    if (k0 + 32 < K) {
#pragma unroll
      for (int i = 0; i < 2; ++i) {
        int o = (i * 256 + tid) * 16;
        int e = o >> 1;
        int row = e >> 5, col = e & 31;
        gload16(A + (size_t)(bm + row) * K + k0 + 32 + col, (char*)sA[buf ^ 1] + o);
        gload16(B + (size_t)(bn + row) * K + k0 + 32 + col, (char*)sB[buf ^ 1] + o);
      }
    }
    bf16x8 af[4], bfr[4];
#pragma unroll
    for (int i = 0; i < 4; ++i) {
      af[i]  = *(const bf16x8*)&sA[buf][(wr + i * 16 + ln) * 32 + quad * 8];
      bfr[i] = *(const bf16x8*)&sB[buf][(wc + i * 16 + ln) * 32 + quad * 8];
    }
#pragma unroll
    for (int i = 0; i < 4; ++i)
#pragma unroll
      for (int j = 0; j < 4; ++j)
        acc[i][j] = __builtin_amdgcn_mfma_f32_16x16x32_bf16(af[i], bfr[j], acc[i][j], 0, 0, 0);
  }

  const int bufi = bn >> 10;                  // 0:q 1:k 2:v (block-uniform)
  const int hq = ((bn & 1023) + wc) >> 6;     // head, wave-uniform
  if (bufi < 2) {
    // ---- q/k with fused RoPE ----
    unsigned short* const base = bufi == 0 ? dq : dk;
    const float qsc = bufi == 0 ? 0.180336880f : 1.0f;  // (1/8)*log2(e) for q
#pragma unroll
    for (int i = 0; i < 4; ++i)
#pragma unroll
      for (int j = 0; j < 4; ++j) {
        int n = bn + wc + j * 16 + ln;
        float bi = bias[n];
        int hd = j * 16 + ln;
        int pi = hd >> 1;
        bool evn = (ln & 1) == 0;
#pragma unroll
        for (int r = 0; r < 4; ++r) {
          int m = bm + wr + i * 16 + quad * 4 + r;
          float val = acc[i][j][r] + bi;
          float par = __shfl_xor(val, 1);
          float c = fc[m * 32 + pi], sn = fs[m * 32 + pi];
          float o = evn ? (val * c - par * sn) : (par * sn + val * c);
          base[((size_t)(hq * S_LEN + m)) * HD + hd] = f2b(o * qsc);
        }
      }
  } else {
    // ---- v: write transposed (h,hd,s) via per-wave LDS scratch ----
    __syncthreads();
    unsigned short* scr =
        (wave < 2 ? (unsigned short*)sA : (unsigned short*)sB) + (wave & 1) * 4096;
#pragma unroll
    for (int i = 0; i < 4; ++i)
#pragma unroll
      for (int j = 0; j < 4; ++j) {
        int n = bn + wc + j * 16 + ln;
        float bi = bias[n];
        int hd = j * 16 + ln;
#pragma unroll
        for (int r = 0; r < 4; ++r) {
          int sl = i * 16 + quad * 4 + r;
          int byte = hd * 128 + ((((sl >> 3) ^ (hd & 7)) << 4)) + (sl & 7) * 2;
          *(unsigned short*)((char*)scr + byte) = f2b(acc[i][j][r] + bi);
        }
      }
#pragma unroll
    for (int pass = 0; pass < 4; ++pass) {
      int row = pass * 16 + ln;
      uint4 d0 = *(uint4*)((char*)scr + row * 128 + (((quad * 2) ^ (row & 7)) << 4));
      uint4 d1 = *(uint4*)((char*)scr + row * 128 + (((quad * 2 + 1) ^ (row & 7)) << 4));
      uint4* dst = (uint4*)(vtout + ((size_t)(hq * HD + row)) * S_LEN + bm + wr + quad * 16);
      dst[0] = d0;
      dst[1] = d1;
    }
  }
}

// ---------------- gemm2: out-proj NT GEMM, 128x64 tile, f32 out -------------------
__global__ __launch_bounds__(256) void gemm_out(
    const unsigned short* __restrict__ A, const unsigned short* __restrict__ B,
    const float* __restrict__ bias, float* __restrict__ outF, int N, int K) {
  __shared__ alignas(16) unsigned short sA[2][128 * 32];
  __shared__ alignas(16) unsigned short sB[2][64 * 32];
  const int tid = threadIdx.x;
  const int lane = tid & 63, wave = tid >> 6;
  const int ln = lane & 15, quad = lane >> 4;
  const int bm = blockIdx.x * 128, bn = blockIdx.y * 64;
  const int wr = (wave >> 1) * 64, wc = (wave & 1) * 32;

  f32x4 acc[4][2];
#pragma unroll
  for (int i = 0; i < 4; ++i)
#pragma unroll
    for (int j = 0; j < 2; ++j) acc[i][j] = fzero4();

  {
#pragma unroll
    for (int i = 0; i < 2; ++i) {
      int o = (i * 256 + tid) * 16;
      int e = o >> 1;
      int row = e >> 5, col = e & 31;
      gload16(A + (size_t)(bm + row) * K + col, (char*)sA[0] + o);
    }
    int o = tid * 16;
    int e = o >> 1;
    int row = e >> 5, col = e & 31;
    gload16(B + (size_t)(bn + row) * K + col, (char*)sB[0] + o);
  }

  int buf = 0;
  for (int k0 = 0; k0 < K; k0 += 32, buf ^= 1) {
    __syncthreads();
    if (k0 + 32 < K) {
#pragma unroll
      for (int i = 0; i < 2; ++i) {
        int o = (i * 256 + tid) * 16;
        int e = o >> 1;
        int row = e >> 5, col = e & 31;
        gload16(A + (size_t)(bm + row) * K + k0 + 32 + col, (char*)sA[buf ^ 1] + o);
      }
      int o = tid * 16;
      int e = o >> 1;
      int row = e >> 5, col = e & 31;
      gload16(B + (size_t)(bn + row) * K + k0 + 32 + col, (char*)sB[buf ^ 1] + o);
    }
    bf16x8 af[4], bfr[2];
#pragma unroll
    for (int i = 0; i < 4; ++i)
      af[i] = *(const bf16x8*)&sA[buf][(wr + i * 16 + ln) * 32 + quad * 8];
#pragma unroll
    for (int j = 0; j < 2; ++j)
      bfr[j] = *(const bf16x8*)&sB[buf][(wc + j * 16 + ln) * 32 + quad * 8];
#pragma unroll
    for (int i = 0; i < 4; ++i)
#pragma unroll
      for (int j = 0; j < 2; ++j)
        acc[i][j] = __builtin_amdgcn_mfma_f32_16x16x32_bf16(af[i], bfr[j], acc[i][j], 0, 0, 0);
  }

#pragma unroll
  for (int i = 0; i < 4; ++i)
#pragma unroll
    for (int j = 0; j < 2; ++j) {
      int n = bn + wc + j * 16 + ln;
      float bi = bias[n];
#pragma unroll
      for (int r = 0; r < 4; ++r) {
        int m = bm + wr + i * 16 + quad * 4 + r;
        outF[(size_t)m * N + n] = acc[i][j][r] + bi;
      }
    }
}

// ---- LDS swizzled 16B read: row-major [64 rows][128B], chunk XOR row&7 ----------
// Read pattern rows 16t+ln at fixed chunk: XOR by ln&7 spreads 8 lanes/bank-group
// in order -> conflict-free (2 lanes/bank = free).
__device__ __forceinline__ bf16x8 lds_swz(const unsigned short* s, int row, int chunk) {
  int byte = row * 128 + ((chunk ^ (row & 7)) << 4);
  return *(const bf16x8*)((const char*)s + byte);
}

// ---------------- Flash attention, causal, exp2 softmax (no running max) ----------
// 1024 blocks x 512 threads. Block c: head h=c&15 (2 heads/XCD -> KV L2-resident),
// q-tile qt=63-(c>>4) (heavy first). All 8 waves share ONE q-tile (wave w of each
// group owns rows qt*64+w*16..+15). Wave-group 0 computes EVEN kv tiles, group 1
// ODD kv tiles -> every wave active every staged step (old shared-sweep left
// group 0 idle 33% of wave-slots). exp2-no-max makes partial (O,l) summable:
// one LDS merge at the end. P never touches LDS: swapped QK^T (mfma(K,Q)) puts
// q on the lane axis; pk2t + permlane32_swap + permlane16_swap rebuild the PV
// A-fragments in-register (16 pack + 8 permlane ops replaces 4 ds_write_b64 +
// 2 ds_read_b128 + lgkm wait per step). 4 staging buffers (2 compute + 2
// prefetch) = 64 KiB LDS -> 2 blocks/CU.
__global__ __launch_bounds__(512, 4) void flash_kernel(
    const unsigned short* __restrict__ qg, const unsigned short* __restrict__ kg,
    const unsigned short* __restrict__ vtg, unsigned short* __restrict__ attn) {
  __shared__ alignas(16) unsigned short sK[2][2][64 * 64];  // [buf][tile-parity]
  __shared__ alignas(16) unsigned short sV[2][2][64 * 64];

  const int tid = threadIdx.x;
  const int lane = tid & 63, wave = tid >> 6;
  const int w = wave & 3, grp = wave >> 2;   // grp 0: even kv tiles, 1: odd
  const int ln = lane & 15, quad = lane >> 4;
  const int c = blockIdx.x;
  const int h = c & 15;
  const int qt = 63 - (c >> 4);              // q-tile index, big blocks first
  const int qrow = qt * 64 + w * 16;

  const unsigned short* qh = qg + (size_t)h * (S_LEN * HD);
  const unsigned short* kh = kg + (size_t)h * (S_LEN * HD);
  const unsigned short* vh = vtg + (size_t)h * (HD * S_LEN);

  bf16x8 qf[2];
  qf[0] = *(const bf16x8*)(qh + (size_t)(qrow + ln) * HD + quad * 8);
  qf[1] = *(const bf16x8*)(qh + (size_t)(qrow + ln) * HD + 32 + quad * 8);

  f32x4 o_acc[4];
  f32x4 l_acc = fzero4();
#pragma unroll
  for (int t = 0; t < 4; ++t) o_acc[t] = fzero4();
  bf16x8 ones;
#pragma unroll
  for (int j = 0; j < 8; ++j) ones[j] = (short)0x3F80;  // bf16 1.0

  const int nst = (qt + 2) >> 1;             // ceil((qt+1)/2) staged steps
  const int srow = tid >> 3, sch = tid & 7;  // 512 threads: 64 rows x 8 chunks
  const int kswz = (sch ^ (srow & 7)) << 3;  // elem offset, matches lds_swz reads

  // preload step 0: tiles 0 (->[0][0]) and 1 (->[0][1]); tile 1 always in-bounds
  gload16(kh + (size_t)srow * HD + kswz, (char*)sK[0][0] + tid * 16);
  gload16(kh + (size_t)(64 + srow) * HD + kswz, (char*)sK[0][1] + tid * 16);
  gload16(vh + (size_t)srow * S_LEN + kswz, (char*)sV[0][0] + tid * 16);
  gload16(vh + (size_t)srow * S_LEN + 64 + kswz, (char*)sV[0][1] + tid * 16);

  int buf = 0;
  for (int s = 0; s < nst; ++s, buf ^= 1) {
    __syncthreads();  // drains DMA for buf; guards buf^1 (read two steps ago)
    if (s + 1 < nst) {
      const int kvE = (2 * s + 2) * 64, kvO = kvE + 64;  // kvO <= 4032 always
      gload16(kh + (size_t)(kvE + srow) * HD + kswz, (char*)sK[buf ^ 1][0] + tid * 16);
      gload16(kh + (size_t)(kvO + srow) * HD + kswz, (char*)sK[buf ^ 1][1] + tid * 16);
      gload16(vh + (size_t)srow * S_LEN + kvE + kswz, (char*)sV[buf ^ 1][0] + tid * 16);
      gload16(vh + (size_t)srow * S_LEN + kvO + kswz, (char*)sV[buf ^ 1][1] + tid * 16);
    }
    const int kt = 2 * s + grp;
    if (kt > qt) continue;  // group-1 tail when qt even (barrier already done)
    const int kv0 = kt * 64;
    const unsigned short* kp = sK[buf][grp];
    const unsigned short* vp = sV[buf][grp];

    // S^T = K Q^T: sc[t] holds rows kv-local 16t+quad*4+r, col q-local ln
    f32x4 sc[4];
#pragma unroll
    for (int t = 0; t < 4; ++t) sc[t] = fzero4();
#pragma unroll
    for (int t = 0; t < 4; ++t) {
      bf16x8 kb0 = lds_swz(kp, t * 16 + ln, quad);
      bf16x8 kb1 = lds_swz(kp, t * 16 + ln, 4 + quad);
      sc[t] = __builtin_amdgcn_mfma_f32_16x16x32_bf16(kb0, qf[0], sc[t], 0, 0, 0);
      sc[t] = __builtin_amdgcn_mfma_f32_16x16x32_bf16(kb1, qf[1], sc[t], 0, 0, 0);
    }

    // p = exp2(s); mask only on the diagonal tile (kt == qt)
    float e[4][4];
    if (kt == qt) {
#pragma unroll
      for (int t = 0; t < 4; ++t)
#pragma unroll
        for (int r = 0; r < 4; ++r) {
          int kvl = 16 * t + quad * 4 + r;
          e[t][r] = (kvl <= w * 16 + ln) ? __builtin_amdgcn_exp2f(sc[t][r]) : 0.0f;
        }
    } else {
#pragma unroll
      for (int t = 0; t < 4; ++t)
#pragma unroll
        for (int r = 0; r < 4; ++r) e[t][r] = __builtin_amdgcn_exp2f(sc[t][r]);
    }

    // In-register P -> A-fragment: lane(ln,quad) needs P[q=ln][kv=8*quad+0..7]
    // (pa0) and [32+8*quad+0..7] (pa1). Sources: kv=16t+4q'+r at lane(ln,q').
    // permlane32_swap then permlane16_swap gathers exactly (t=quad>>1,
    // q'=2(quad&1)+{0,1}) — verified lane-by-lane.
    unsigned int x0 = pk2t(e[0][0], e[0][1]), x1 = pk2t(e[0][2], e[0][3]);
    unsigned int y0 = pk2t(e[1][0], e[1][1]), y1 = pk2t(e[1][2], e[1][3]);
    unsigned int z0 = pk2t(e[2][0], e[2][1]), z1 = pk2t(e[2][2], e[2][3]);
    unsigned int w0 = pk2t(e[3][0], e[3][1]), w1 = pk2t(e[3][2], e[3][3]);
    auto a32 = __builtin_amdgcn_permlane32_swap(x0, y0, false, false);
    auto a16 = __builtin_amdgcn_permlane16_swap(a32[0], a32[1], false, false);
    auto b32 = __builtin_amdgcn_permlane32_swap(x1, y1, false, false);
    auto b16 = __builtin_amdgcn_permlane16_swap(b32[0], b32[1], false, false);
    auto c32 = __builtin_amdgcn_permlane32_swap(z0, w0, false, false);
    auto c16 = __builtin_amdgcn_permlane16_swap(c32[0], c32[1], false, false);
    auto d32 = __builtin_amdgcn_permlane32_swap(z1, w1, false, false);
    auto d16 = __builtin_amdgcn_permlane16_swap(d32[0], d32[1], false, false);
    union { uint4 u; bf16x8 b; } pa0u, pa1u;
    pa0u.u = make_uint4(a16[0], b16[0], a16[1], b16[1]);
    pa1u.u = make_uint4(c16[0], d16[0], c16[1], d16[1]);
    const bf16x8 pa0 = pa0u.b, pa1 = pa1u.b;

    // l += P @ ones
    l_acc = __builtin_amdgcn_mfma_f32_16x16x32_bf16(pa0, ones, l_acc, 0, 0, 0);
    l_acc = __builtin_amdgcn_mfma_f32_16x16x32_bf16(pa1, ones, l_acc, 0, 0, 0);

    // O += P @ V
#pragma unroll
    for (int t = 0; t < 4; ++t) {
      bf16x8 vb0 = lds_swz(vp, t * 16 + ln, quad);
      bf16x8 vb1 = lds_swz(vp, t * 16 + ln, 4 + quad);
      o_acc[t] = __builtin_amdgcn_mfma_f32_16x16x32_bf16(pa0, vb0, o_acc[t], 0, 0, 0);
      o_acc[t] = __builtin_amdgcn_mfma_f32_16x16x32_bf16(pa1, vb1, o_acc[t], 0, 0, 0);
    }
  }

  // merge group 1's partial (O,l) into group 0 via LDS (reuse sK), then epilogue
  __syncthreads();  // all compute done; no DMA in flight
  float* mrg = (float*)sK;
  const int mi = (w * 64 + lane) * 20;  // 20 f32/lane, 16B-aligned blob
  if (grp == 1) {
    *(f32x4*)&mrg[mi +  0] = o_acc[0];
    *(f32x4*)&mrg[mi +  4] = o_acc[1];
    *(f32x4*)&mrg[mi +  8] = o_acc[2];
    *(f32x4*)&mrg[mi + 12] = o_acc[3];
    *(f32x4*)&mrg[mi + 16] = l_acc;
  }
  __syncthreads();
  if (grp == 0) {
    o_acc[0] += *(const f32x4*)&mrg[mi + 0];
    o_acc[1] += *(const f32x4*)&mrg[mi + 4];
    o_acc[2] += *(const f32x4*)&mrg[mi + 8];
    o_acc[3] += *(const f32x4*)&mrg[mi + 12];
    l_acc += *(const f32x4*)&mrg[mi + 16];
    float inv[4];
#pragma unroll
    for (int r = 0; r < 4; ++r) inv[r] = 1.0f / l_acc[r];
#pragma unroll
    for (int t = 0; t < 4; ++t)
#pragma unroll
      for (int r = 0; r < 4; ++r) {
        int row = qrow + quad * 4 + r;
        attn[(size_t)row * DIM + h * HD + t * 16 + ln] = f2b(o_acc[t][r] * inv[r]);
      }
  }
}

extern "C" void kernel_launch(void* const* d_in, const int* in_sizes, int n_in,
                              void* d_out, int out_size, void* d_ws, size_t ws_size,
                              hipStream_t stream) {
  const float* x    = (const float*)d_in[0];
  const float* fc   = (const float*)d_in[2];
  const float* fs   = (const float*)d_in[3];
  const float* wqw  = (const float*)d_in[5];
  const float* wqb  = (const float*)d_in[6];
  const float* wkw  = (const float*)d_in[7];
  const float* wkb  = (const float*)d_in[8];
  const float* wvw  = (const float*)d_in[9];
  const float* wvb  = (const float*)d_in[10];
  const float* wow  = (const float*)d_in[11];
  const float* wobf = (const float*)d_in[12];
  float* out = (float*)d_out;

  char* ws = (char*)d_ws;
  const size_t MB = (size_t)1 << 20;
  unsigned short* xb    = (unsigned short*)(ws + 0);
  unsigned short* wqkvb = (unsigned short*)(ws + 8 * MB);
  unsigned short* wobb  = (unsigned short*)(ws + 16 * MB);
  float* biasq = (float*)(ws + 18 * MB);
  float* biaso = (float*)(ws + 18 * MB + 65536);
  unsigned short* qb_ = (unsigned short*)(ws + 19 * MB);
  unsigned short* kb_ = (unsigned short*)(ws + 27 * MB);
  unsigned short* vt  = (unsigned short*)(ws + 35 * MB);  // vT written by gemm1
  unsigned short* attn = (unsigned short*)(ws + 0);       // aliases xb (dead after gemm1)

  cvt_all<<<8196, 256, 0, stream>>>(x, wqw, wkw, wvw, wow, wqb, wkb, wvb, wobf,
                                    xb, wqkvb, wobb, biasq, biaso);
  gemm_qkv<<<dim3(32, 24), 256, 0, stream>>>(xb, wqkvb, biasq, qb_, kb_, vt, fc, fs, 1024);
  flash_kernel<<<1024, 512, 0, stream>>>(qb_, kb_, vt, attn);
  gemm_out<<<dim3(32, 16), 256, 0, stream>>>(attn, wobb, biaso, out, 1024, 1024);
}

// Round 2
// 248.871 us; speedup vs baseline: 1.0709x; 1.0039x over previous
//
#include <hip/hip_runtime.h>

// AttentionLoRA: B=1, S=4096, D=1024, H=16, HD=64.
// Pipeline (4 kernels):
//   cvt_all (f32->bf16 + bias pack)
//   gemm1: QKV NT-GEMM, 256x256 tile / BK=64 / 8 waves (2x4) / 128KB dbuf LDS,
//          2-phase sync (1 barrier per K-step, prefetch-before-compute),
//          both-sides LDS swizzle (pre-swizzled global src + swizzled ds_read).
//          Epilogue fuses RoPE (q/k) and V-transpose -> vT (h,hd,s).
//   flash: causal, exp2 softmax (no running max -> partial O,l summable);
//          1024 blocks x 512 thr, even/odd kv-tile split across wave groups,
//          in-register P via swapped QK^T + pk2t + permlane swaps.
//   gemm2: out-proj, 128x64 tiles (512 blocks, 2/CU), f32 out.

#define S_LEN 4096
#define DIM   1024
#define NH    16
#define HD    64

typedef __attribute__((ext_vector_type(8))) short bf16x8;   // 8 bf16 = 4 VGPRs
typedef __attribute__((ext_vector_type(4))) float f32x4;

__device__ __forceinline__ unsigned short f2b(float f) {
  union { float f; unsigned int u; } v; v.f = f;
  unsigned int r = (v.u + 0x7fffu + ((v.u >> 16) & 1u)) >> 16;  // RNE
  return (unsigned short)r;
}
__device__ __forceinline__ float b2f(unsigned short h) {
  union { unsigned int u; float f; } v; v.u = ((unsigned int)h) << 16;
  return v.f;
}
// pack two f32 -> two bf16 by truncation (<=1ulp)
__device__ __forceinline__ unsigned int pk2t(float a, float b) {
  union { float f; unsigned int u; } x, y; x.f = a; y.f = b;
  return (x.u >> 16) | (y.u & 0xffff0000u);
}
__device__ __forceinline__ void gload16(const void* g, void* l) {
  __builtin_amdgcn_global_load_lds(
      (const __attribute__((address_space(1))) unsigned int*)g,
      (__attribute__((address_space(3))) unsigned int*)l, 16, 0, 0);
}
__device__ __forceinline__ f32x4 fzero4() { f32x4 z = {0.f, 0.f, 0.f, 0.f}; return z; }

// ---- LDS swizzled 16B read: row-major [rows][128B], chunk XOR row&7 -------------
// Staging pre-swizzles the GLOBAL source column by the same XOR, LDS stays linear
// (global_load_lds constraint), read applies the XOR -> both sides consistent.
// 64 lanes land 8 per 16B bank-group = conflict-free for ds_read_b128.
__device__ __forceinline__ bf16x8 lds_swz(const unsigned short* s, int row, int chunk) {
  int byte = row * 128 + ((chunk ^ (row & 7)) << 4);
  return *(const bf16x8*)((const char*)s + byte);
}

// ---------------- fused f32->bf16 convert (x, wq, wk, wv, wo) + bias pack ----------
__global__ void cvt_all(const float* __restrict__ x, const float* __restrict__ wq,
                        const float* __restrict__ wk, const float* __restrict__ wv,
                        const float* __restrict__ wo, const float* __restrict__ qb,
                        const float* __restrict__ kb, const float* __restrict__ vbs,
                        const float* __restrict__ ob, unsigned short* __restrict__ xb,
                        unsigned short* __restrict__ wqkvb, unsigned short* __restrict__ wobb,
                        float* __restrict__ biasq, float* __restrict__ biaso) {
  int i = blockIdx.x * 256 + threadIdx.x;  // float4 index
  if (i < 2097152) {
    const float* src; unsigned short* dst; int off;
    if (i < 1048576)      { src = x;  dst = xb;              off = i; }
    else if (i < 1310720) { src = wq; dst = wqkvb;           off = i - 1048576; }
    else if (i < 1572864) { src = wk; dst = wqkvb + 1048576; off = i - 1310720; }
    else if (i < 1835008) { src = wv; dst = wqkvb + 2097152; off = i - 1572864; }
    else                  { src = wo; dst = wobb;            off = i - 1835008; }
    float4 v = ((const float4*)src)[off];
    unsigned int lo = (unsigned int)f2b(v.x) | ((unsigned int)f2b(v.y) << 16);
    unsigned int hi = (unsigned int)f2b(v.z) | ((unsigned int)f2b(v.w) << 16);
    ((uint2*)dst)[off] = make_uint2(lo, hi);
  } else if (i < 2097152 + 1024) {
    int j = i - 2097152;
    if (j < 256)      ((float4*)biasq)[j]              = ((const float4*)qb)[j];
    else if (j < 512) ((float4*)(biasq + 1024))[j-256] = ((const float4*)kb)[j-256];
    else if (j < 768) ((float4*)(biasq + 2048))[j-512] = ((const float4*)vbs)[j-512];
    else              ((float4*)biaso)[j-768]          = ((const float4*)ob)[j-768];
  }
}

// ---------------- gemm1: QKV NT-GEMM, 256x256/BK=64/8 waves, fused epilogue -------
// Grid (16,12): 192 blocks, 1/CU (128KB LDS). Per wave 128x64 output (M_rep=8,
// N_rep=4). Per K-step: 8 gload16/thread staging (pre-swizzled src), 24
// ds_read_b128 + 64 MFMA per wave. K order identical to the 128² version ->
// bit-identical accumulation.
__global__ __launch_bounds__(512, 2) void gemm_qkv(
    const unsigned short* __restrict__ A, const unsigned short* __restrict__ B,
    const float* __restrict__ bias, unsigned short* __restrict__ dq,
    unsigned short* __restrict__ dk, unsigned short* __restrict__ vtout,
    const float* __restrict__ fc, const float* __restrict__ fs, int K) {
  __shared__ alignas(16) unsigned short sA[2][256 * 64];  // 64KB
  __shared__ alignas(16) unsigned short sB[2][256 * 64];  // 64KB
  const int tid = threadIdx.x;
  const int lane = tid & 63, wave = tid >> 6;
  const int ln = lane & 15, quad = lane >> 4;
  const int bm = blockIdx.x * 256, bn = blockIdx.y * 256;
  const int wr = (wave >> 2) * 128, wc = (wave & 3) * 64;

  f32x4 acc[8][4];
#pragma unroll
  for (int i = 0; i < 8; ++i)
#pragma unroll
    for (int j = 0; j < 4; ++j) acc[i][j] = fzero4();

  // staging geometry: elem o = (i*512+tid)*8; row = o>>6, chunk c = (o>>3)&7.
  // source column pre-swizzled by c^(row&7); LDS linear at byte o*2.
#pragma unroll
  for (int i = 0; i < 4; ++i) {
    int o = (i * 512 + tid) * 8;
    int row = o >> 6, c = (o >> 3) & 7;
    int col = ((c ^ (row & 7)) << 3);
    gload16(A + (size_t)(bm + row) * K + col, (char*)sA[0] + o * 2);
    gload16(B + (size_t)(bn + row) * K + col, (char*)sB[0] + o * 2);
  }

  int buf = 0;
  for (int k0 = 0; k0 < K; k0 += 64, buf ^= 1) {
    __syncthreads();  // drains DMA for buf; guards buf^1
    if (k0 + 64 < K) {
#pragma unroll
      for (int i = 0; i < 4; ++i) {
        int o = (i * 512 + tid) * 8;
        int row = o >> 6, c = (o >> 3) & 7;
        int col = k0 + 64 + ((c ^ (row & 7)) << 3);
        gload16(A + (size_t)(bm + row) * K + col, (char*)sA[buf ^ 1] + o * 2);
        gload16(B + (size_t)(bn + row) * K + col, (char*)sB[buf ^ 1] + o * 2);
      }
    }
#pragma unroll
    for (int ks = 0; ks < 2; ++ks) {
      bf16x8 af[8], bfr[4];
#pragma unroll
      for (int i = 0; i < 8; ++i)
        af[i] = lds_swz(sA[buf], wr + i * 16 + ln, ks * 4 + quad);
#pragma unroll
      for (int j = 0; j < 4; ++j)
        bfr[j] = lds_swz(sB[buf], wc + j * 16 + ln, ks * 4 + quad);
#pragma unroll
      for (int i = 0; i < 8; ++i)
#pragma unroll
        for (int j = 0; j < 4; ++j)
          acc[i][j] = __builtin_amdgcn_mfma_f32_16x16x32_bf16(af[i], bfr[j], acc[i][j], 0, 0, 0);
    }
  }

  const int bufi = bn >> 10;                  // 0:q 1:k 2:v (block-uniform)
  const int hq = ((bn & 1023) + wc) >> 6;     // head, wave-uniform (wc mult of 64)
  if (bufi < 2) {
    // ---- q/k with fused RoPE ----
    unsigned short* const base = bufi == 0 ? dq : dk;
    const float qsc = bufi == 0 ? 0.180336880f : 1.0f;  // (1/8)*log2(e) for q
#pragma unroll
    for (int i = 0; i < 8; ++i)
#pragma unroll
      for (int j = 0; j < 4; ++j) {
        int n = bn + wc + j * 16 + ln;
        float bi = bias[n];
        int hd = j * 16 + ln;
        int pi = hd >> 1;
        bool evn = (ln & 1) == 0;
#pragma unroll
        for (int r = 0; r < 4; ++r) {
          int m = bm + wr + i * 16 + quad * 4 + r;
          float val = acc[i][j][r] + bi;
          float par = __shfl_xor(val, 1);
          float c = fc[m * 32 + pi], sn = fs[m * 32 + pi];
          float o = evn ? (val * c - par * sn) : (par * sn + val * c);
          base[((size_t)(hq * S_LEN + m)) * HD + hd] = f2b(o * qsc);
        }
      }
  } else {
    // ---- v: write transposed (h,hd,s) via per-wave LDS scratch [64 hd][128 s] ----
    __syncthreads();  // main-loop reads done; reuse sA/sB as 8x16KB scratch
    unsigned short* scr =
        (wave < 4 ? (unsigned short*)sA : (unsigned short*)sB) + (wave & 3) * 8192;
#pragma unroll
    for (int i = 0; i < 8; ++i)
#pragma unroll
      for (int j = 0; j < 4; ++j) {
        int n = bn + wc + j * 16 + ln;
        float bi = bias[n];
        int hd = j * 16 + ln;
#pragma unroll
        for (int r = 0; r < 4; ++r) {
          int sl = i * 16 + quad * 4 + r;                     // 0..127 (s-local)
          int byte = hd * 256 + ((((sl >> 3) ^ (hd & 7)) << 4)) + (sl & 7) * 2;
          *(unsigned short*)((char*)scr + byte) = f2b(acc[i][j][r] + bi);
        }
      }
#pragma unroll
    for (int pass = 0; pass < 4; ++pass) {
      int row = pass * 16 + ln;  // hd
      uint4 d[4];
#pragma unroll
      for (int j = 0; j < 4; ++j) {
        int c = quad * 4 + j;  // 16B chunk = 8 s-elements
        d[j] = *(uint4*)((char*)scr + row * 256 + ((c ^ (row & 7)) << 4));
      }
      uint4* dst = (uint4*)(vtout + ((size_t)(hq * HD + row)) * S_LEN + bm + wr + quad * 32);
#pragma unroll
      for (int j = 0; j < 4; ++j) dst[j] = d[j];
    }
  }
}

// ---------------- gemm2: out-proj NT GEMM, 128x64 tile, f32 out -------------------
__global__ __launch_bounds__(256) void gemm_out(
    const unsigned short* __restrict__ A, const unsigned short* __restrict__ B,
    const float* __restrict__ bias, float* __restrict__ outF, int N, int K) {
  __shared__ alignas(16) unsigned short sA[2][128 * 32];
  __shared__ alignas(16) unsigned short sB[2][64 * 32];
  const int tid = threadIdx.x;
  const int lane = tid & 63, wave = tid >> 6;
  const int ln = lane & 15, quad = lane >> 4;
  const int bm = blockIdx.x * 128, bn = blockIdx.y * 64;
  const int wr = (wave >> 1) * 64, wc = (wave & 1) * 32;

  f32x4 acc[4][2];
#pragma unroll
  for (int i = 0; i < 4; ++i)
#pragma unroll
    for (int j = 0; j < 2; ++j) acc[i][j] = fzero4();

  {
#pragma unroll
    for (int i = 0; i < 2; ++i) {
      int o = (i * 256 + tid) * 16;
      int e = o >> 1;
      int row = e >> 5, col = e & 31;
      gload16(A + (size_t)(bm + row) * K + col, (char*)sA[0] + o);
    }
    int o = tid * 16;
    int e = o >> 1;
    int row = e >> 5, col = e & 31;
    gload16(B + (size_t)(bn + row) * K + col, (char*)sB[0] + o);
  }

  int buf = 0;
  for (int k0 = 0; k0 < K; k0 += 32, buf ^= 1) {
    __syncthreads();
    if (k0 + 32 < K) {
#pragma unroll
      for (int i = 0; i < 2; ++i) {
        int o = (i * 256 + tid) * 16;
        int e = o >> 1;
        int row = e >> 5, col = e & 31;
        gload16(A + (size_t)(bm + row) * K + k0 + 32 + col, (char*)sA[buf ^ 1] + o);
      }
      int o = tid * 16;
      int e = o >> 1;
      int row = e >> 5, col = e & 31;
      gload16(B + (size_t)(bn + row) * K + k0 + 32 + col, (char*)sB[buf ^ 1] + o);
    }
    bf16x8 af[4], bfr[2];
#pragma unroll
    for (int i = 0; i < 4; ++i)
      af[i] = *(const bf16x8*)&sA[buf][(wr + i * 16 + ln) * 32 + quad * 8];
#pragma unroll
    for (int j = 0; j < 2; ++j)
      bfr[j] = *(const bf16x8*)&sB[buf][(wc + j * 16 + ln) * 32 + quad * 8];
#pragma unroll
    for (int i = 0; i < 4; ++i)
#pragma unroll
      for (int j = 0; j < 2; ++j)
        acc[i][j] = __builtin_amdgcn_mfma_f32_16x16x32_bf16(af[i], bfr[j], acc[i][j], 0, 0, 0);
  }

#pragma unroll
  for (int i = 0; i < 4; ++i)
#pragma unroll
    for (int j = 0; j < 2; ++j) {
      int n = bn + wc + j * 16 + ln;
      float bi = bias[n];
#pragma unroll
      for (int r = 0; r < 4; ++r) {
        int m = bm + wr + i * 16 + quad * 4 + r;
        outF[(size_t)m * N + n] = acc[i][j][r] + bi;
      }
    }
}

// ---------------- Flash attention, causal, exp2 softmax (no running max) ----------
// 1024 blocks x 512 threads. Block c: head h=c&15 (2 heads/XCD -> KV L2-resident),
// q-tile qt=63-(c>>4) (heavy first). Wave-group 0 computes EVEN kv tiles, group 1
// ODD kv tiles -> every wave active every staged step. exp2-no-max makes partial
// (O,l) summable: one LDS merge at the end. P fully in-register via swapped QK^T
// (mfma(K,Q)) + pk2t + permlane32/16_swap. 4 staging buffers = 64KB LDS.
__global__ __launch_bounds__(512, 4) void flash_kernel(
    const unsigned short* __restrict__ qg, const unsigned short* __restrict__ kg,
    const unsigned short* __restrict__ vtg, unsigned short* __restrict__ attn) {
  __shared__ alignas(16) unsigned short sK[2][2][64 * 64];  // [buf][tile-parity]
  __shared__ alignas(16) unsigned short sV[2][2][64 * 64];

  const int tid = threadIdx.x;
  const int lane = tid & 63, wave = tid >> 6;
  const int w = wave & 3, grp = wave >> 2;   // grp 0: even kv tiles, 1: odd
  const int ln = lane & 15, quad = lane >> 4;
  const int c = blockIdx.x;
  const int h = c & 15;
  const int qt = 63 - (c >> 4);              // q-tile index, big blocks first
  const int qrow = qt * 64 + w * 16;

  const unsigned short* qh = qg + (size_t)h * (S_LEN * HD);
  const unsigned short* kh = kg + (size_t)h * (S_LEN * HD);
  const unsigned short* vh = vtg + (size_t)h * (HD * S_LEN);

  bf16x8 qf[2];
  qf[0] = *(const bf16x8*)(qh + (size_t)(qrow + ln) * HD + quad * 8);
  qf[1] = *(const bf16x8*)(qh + (size_t)(qrow + ln) * HD + 32 + quad * 8);

  f32x4 o_acc[4];
  f32x4 l_acc = fzero4();
#pragma unroll
  for (int t = 0; t < 4; ++t) o_acc[t] = fzero4();
  bf16x8 ones;
#pragma unroll
  for (int j = 0; j < 8; ++j) ones[j] = (short)0x3F80;  // bf16 1.0

  const int nst = (qt + 2) >> 1;             // ceil((qt+1)/2) staged steps
  const int srow = tid >> 3, sch = tid & 7;  // 512 threads: 64 rows x 8 chunks
  const int kswz = (sch ^ (srow & 7)) << 3;  // elem offset, matches lds_swz reads

  // preload step 0: tiles 0 (->[0][0]) and 1 (->[0][1]); tile 1 always in-bounds
  gload16(kh + (size_t)srow * HD + kswz, (char*)sK[0][0] + tid * 16);
  gload16(kh + (size_t)(64 + srow) * HD + kswz, (char*)sK[0][1] + tid * 16);
  gload16(vh + (size_t)srow * S_LEN + kswz, (char*)sV[0][0] + tid * 16);
  gload16(vh + (size_t)srow * S_LEN + 64 + kswz, (char*)sV[0][1] + tid * 16);

  int buf = 0;
  for (int s = 0; s < nst; ++s, buf ^= 1) {
    __syncthreads();  // drains DMA for buf; guards buf^1 (read two steps ago)
    if (s + 1 < nst) {
      const int kvE = (2 * s + 2) * 64, kvO = kvE + 64;  // kvO <= 4032 always
      gload16(kh + (size_t)(kvE + srow) * HD + kswz, (char*)sK[buf ^ 1][0] + tid * 16);
      gload16(kh + (size_t)(kvO + srow) * HD + kswz, (char*)sK[buf ^ 1][1] + tid * 16);
      gload16(vh + (size_t)srow * S_LEN + kvE + kswz, (char*)sV[buf ^ 1][0] + tid * 16);
      gload16(vh + (size_t)srow * S_LEN + kvO + kswz, (char*)sV[buf ^ 1][1] + tid * 16);
    }
    const int kt = 2 * s + grp;
    if (kt > qt) continue;  // group-1 tail when qt even (barrier already done)
    const unsigned short* kp = sK[buf][grp];
    const unsigned short* vp = sV[buf][grp];

    // S^T = K Q^T: sc[t] holds rows kv-local 16t+quad*4+r, col q-local ln
    f32x4 sc[4];
#pragma unroll
    for (int t = 0; t < 4; ++t) sc[t] = fzero4();
#pragma unroll
    for (int t = 0; t < 4; ++t) {
      bf16x8 kb0 = lds_swz(kp, t * 16 + ln, quad);
      bf16x8 kb1 = lds_swz(kp, t * 16 + ln, 4 + quad);
      sc[t] = __builtin_amdgcn_mfma_f32_16x16x32_bf16(kb0, qf[0], sc[t], 0, 0, 0);
      sc[t] = __builtin_amdgcn_mfma_f32_16x16x32_bf16(kb1, qf[1], sc[t], 0, 0, 0);
    }

    // p = exp2(s); mask only on the diagonal tile (kt == qt)
    float e[4][4];
    if (kt == qt) {
#pragma unroll
      for (int t = 0; t < 4; ++t)
#pragma unroll
        for (int r = 0; r < 4; ++r) {
          int kvl = 16 * t + quad * 4 + r;
          e[t][r] = (kvl <= w * 16 + ln) ? __builtin_amdgcn_exp2f(sc[t][r]) : 0.0f;
        }
    } else {
#pragma unroll
      for (int t = 0; t < 4; ++t)
#pragma unroll
        for (int r = 0; r < 4; ++r) e[t][r] = __builtin_amdgcn_exp2f(sc[t][r]);
    }

    // In-register P -> A-fragment: lane(ln,quad) needs P[q=ln][kv=8*quad+0..7]
    // (pa0) and [32+8*quad+0..7] (pa1). permlane32_swap then permlane16_swap
    // gathers exactly (t=quad>>1, q'=2(quad&1)+{0,1}).
    unsigned int x0 = pk2t(e[0][0], e[0][1]), x1 = pk2t(e[0][2], e[0][3]);
    unsigned int y0 = pk2t(e[1][0], e[1][1]), y1 = pk2t(e[1][2], e[1][3]);
    unsigned int z0 = pk2t(e[2][0], e[2][1]), z1 = pk2t(e[2][2], e[2][3]);
    unsigned int w0 = pk2t(e[3][0], e[3][1]), w1 = pk2t(e[3][2], e[3][3]);
    auto a32 = __builtin_amdgcn_permlane32_swap(x0, y0, false, false);
    auto a16 = __builtin_amdgcn_permlane16_swap(a32[0], a32[1], false, false);
    auto b32 = __builtin_amdgcn_permlane32_swap(x1, y1, false, false);
    auto b16 = __builtin_amdgcn_permlane16_swap(b32[0], b32[1], false, false);
    auto c32 = __builtin_amdgcn_permlane32_swap(z0, w0, false, false);
    auto c16 = __builtin_amdgcn_permlane16_swap(c32[0], c32[1], false, false);
    auto d32 = __builtin_amdgcn_permlane32_swap(z1, w1, false, false);
    auto d16 = __builtin_amdgcn_permlane16_swap(d32[0], d32[1], false, false);
    union { uint4 u; bf16x8 b; } pa0u, pa1u;
    pa0u.u = make_uint4(a16[0], b16[0], a16[1], b16[1]);
    pa1u.u = make_uint4(c16[0], d16[0], c16[1], d16[1]);
    const bf16x8 pa0 = pa0u.b, pa1 = pa1u.b;

    // l += P @ ones
    l_acc = __builtin_amdgcn_mfma_f32_16x16x32_bf16(pa0, ones, l_acc, 0, 0, 0);
    l_acc = __builtin_amdgcn_mfma_f32_16x16x32_bf16(pa1, ones, l_acc, 0, 0, 0);

    // O += P @ V
#pragma unroll
    for (int t = 0; t < 4; ++t) {
      bf16x8 vb0 = lds_swz(vp, t * 16 + ln, quad);
      bf16x8 vb1 = lds_swz(vp, t * 16 + ln, 4 + quad);
      o_acc[t] = __builtin_amdgcn_mfma_f32_16x16x32_bf16(pa0, vb0, o_acc[t], 0, 0, 0);
      o_acc[t] = __builtin_amdgcn_mfma_f32_16x16x32_bf16(pa1, vb1, o_acc[t], 0, 0, 0);
    }
  }

  // merge group 1's partial (O,l) into group 0 via LDS (reuse sK), then epilogue
  __syncthreads();  // all compute done; no DMA in flight
  float* mrg = (float*)sK;
  const int mi = (w * 64 + lane) * 20;  // 20 f32/lane, 16B-aligned blob
  if (grp == 1) {
    *(f32x4*)&mrg[mi +  0] = o_acc[0];
    *(f32x4*)&mrg[mi +  4] = o_acc[1];
    *(f32x4*)&mrg[mi +  8] = o_acc[2];
    *(f32x4*)&mrg[mi + 12] = o_acc[3];
    *(f32x4*)&mrg[mi + 16] = l_acc;
  }
  __syncthreads();
  if (grp == 0) {
    o_acc[0] += *(const f32x4*)&mrg[mi + 0];
    o_acc[1] += *(const f32x4*)&mrg[mi + 4];
    o_acc[2] += *(const f32x4*)&mrg[mi + 8];
    o_acc[3] += *(const f32x4*)&mrg[mi + 12];
    l_acc += *(const f32x4*)&mrg[mi + 16];
    float inv[4];
#pragma unroll
    for (int r = 0; r < 4; ++r) inv[r] = 1.0f / l_acc[r];
#pragma unroll
    for (int t = 0; t < 4; ++t)
#pragma unroll
      for (int r = 0; r < 4; ++r) {
        int row = qrow + quad * 4 + r;
        attn[(size_t)row * DIM + h * HD + t * 16 + ln] = f2b(o_acc[t][r] * inv[r]);
      }
  }
}

extern "C" void kernel_launch(void* const* d_in, const int* in_sizes, int n_in,
                              void* d_out, int out_size, void* d_ws, size_t ws_size,
                              hipStream_t stream) {
  const float* x    = (const float*)d_in[0];
  const float* fc   = (const float*)d_in[2];
  const float* fs   = (const float*)d_in[3];
  const float* wqw  = (const float*)d_in[5];
  const float* wqb  = (const float*)d_in[6];
  const float* wkw  = (const float*)d_in[7];
  const float* wkb  = (const float*)d_in[8];
  const float* wvw  = (const float*)d_in[9];
  const float* wvb  = (const float*)d_in[10];
  const float* wow  = (const float*)d_in[11];
  const float* wobf = (const float*)d_in[12];
  float* out = (float*)d_out;

  char* ws = (char*)d_ws;
  const size_t MB = (size_t)1 << 20;
  unsigned short* xb    = (unsigned short*)(ws + 0);
  unsigned short* wqkvb = (unsigned short*)(ws + 8 * MB);
  unsigned short* wobb  = (unsigned short*)(ws + 16 * MB);
  float* biasq = (float*)(ws + 18 * MB);
  float* biaso = (float*)(ws + 18 * MB + 65536);
  unsigned short* qb_ = (unsigned short*)(ws + 19 * MB);
  unsigned short* kb_ = (unsigned short*)(ws + 27 * MB);
  unsigned short* vt  = (unsigned short*)(ws + 35 * MB);  // vT written by gemm1
  unsigned short* attn = (unsigned short*)(ws + 0);       // aliases xb (dead after gemm1)

  cvt_all<<<8196, 256, 0, stream>>>(x, wqw, wkw, wvw, wow, wqb, wkb, wvb, wobf,
                                    xb, wqkvb, wobb, biasq, biaso);
  gemm_qkv<<<dim3(16, 12), 512, 0, stream>>>(xb, wqkvb, biasq, qb_, kb_, vt, fc, fs, 1024);
  flash_kernel<<<1024, 512, 0, stream>>>(qb_, kb_, vt, attn);
  gemm_out<<<dim3(32, 16), 256, 0, stream>>>(attn, wobb, biaso, out, 1024, 1024);
}

// Round 3
// 248.232 us; speedup vs baseline: 1.0736x; 1.0026x over previous
//
#include <hip/hip_runtime.h>

// AttentionLoRA: B=1, S=4096, D=1024, H=16, HD=64.
// Pipeline (4 kernels):
//   cvt_all (f32->bf16 + bias pack)
//   gemm1: QKV NT-GEMM, 256x256 tile / BK=64 / 8 waves (2x4) / 128KB dbuf LDS,
//          **8-phase schedule with counted vmcnt** (T3+T4): per K-tile 4 phases,
//          each {8 ds_read_b128 | 2 gload16 stage-chunk | bar | lgkm0 | setprio
//          16 MFMA | bar}; vmcnt(2) only at tile boundaries (never 0 mid-loop).
//          Both-sides LDS swizzle (pre-swizzled global src + swizzled ds_read).
//          Epilogue fuses RoPE (q/k) and V-transpose -> vT (h,hd,s).
//   flash: causal, exp2 softmax (no running max -> partial O,l summable);
//          1024 blocks x 512 thr, even/odd kv-tile split across wave groups,
//          in-register P via swapped QK^T + pk2t + permlane swaps.
//   gemm2: out-proj, 128x64 tiles (512 blocks, 2/CU), f32 out.

#define S_LEN 4096
#define DIM   1024
#define NH    16
#define HD    64

typedef __attribute__((ext_vector_type(8))) short bf16x8;   // 8 bf16 = 4 VGPRs
typedef __attribute__((ext_vector_type(4))) float f32x4;

__device__ __forceinline__ unsigned short f2b(float f) {
  union { float f; unsigned int u; } v; v.f = f;
  unsigned int r = (v.u + 0x7fffu + ((v.u >> 16) & 1u)) >> 16;  // RNE
  return (unsigned short)r;
}
__device__ __forceinline__ float b2f(unsigned short h) {
  union { unsigned int u; float f; } v; v.u = ((unsigned int)h) << 16;
  return v.f;
}
// pack two f32 -> two bf16 by truncation (<=1ulp)
__device__ __forceinline__ unsigned int pk2t(float a, float b) {
  union { float f; unsigned int u; } x, y; x.f = a; y.f = b;
  return (x.u >> 16) | (y.u & 0xffff0000u);
}
__device__ __forceinline__ void gload16(const void* g, void* l) {
  __builtin_amdgcn_global_load_lds(
      (const __attribute__((address_space(1))) unsigned int*)g,
      (__attribute__((address_space(3))) unsigned int*)l, 16, 0, 0);
}
__device__ __forceinline__ f32x4 fzero4() { f32x4 z = {0.f, 0.f, 0.f, 0.f}; return z; }

// ---- LDS swizzled 16B read: row-major [rows][128B], chunk XOR row&7 -------------
// Staging pre-swizzles the GLOBAL source column by the same XOR, LDS stays linear
// (global_load_lds constraint), read applies the XOR -> both sides consistent.
__device__ __forceinline__ bf16x8 lds_swz(const unsigned short* s, int row, int chunk) {
  int byte = row * 128 + ((chunk ^ (row & 7)) << 4);
  return *(const bf16x8*)((const char*)s + byte);
}

// ---------------- fused f32->bf16 convert (x, wq, wk, wv, wo) + bias pack ----------
__global__ void cvt_all(const float* __restrict__ x, const float* __restrict__ wq,
                        const float* __restrict__ wk, const float* __restrict__ wv,
                        const float* __restrict__ wo, const float* __restrict__ qb,
                        const float* __restrict__ kb, const float* __restrict__ vbs,
                        const float* __restrict__ ob, unsigned short* __restrict__ xb,
                        unsigned short* __restrict__ wqkvb, unsigned short* __restrict__ wobb,
                        float* __restrict__ biasq, float* __restrict__ biaso) {
  int i = blockIdx.x * 256 + threadIdx.x;  // float4 index
  if (i < 2097152) {
    const float* src; unsigned short* dst; int off;
    if (i < 1048576)      { src = x;  dst = xb;              off = i; }
    else if (i < 1310720) { src = wq; dst = wqkvb;           off = i - 1048576; }
    else if (i < 1572864) { src = wk; dst = wqkvb + 1048576; off = i - 1310720; }
    else if (i < 1835008) { src = wv; dst = wqkvb + 2097152; off = i - 1572864; }
    else                  { src = wo; dst = wobb;            off = i - 1835008; }
    float4 v = ((const float4*)src)[off];
    unsigned int lo = (unsigned int)f2b(v.x) | ((unsigned int)f2b(v.y) << 16);
    unsigned int hi = (unsigned int)f2b(v.z) | ((unsigned int)f2b(v.w) << 16);
    ((uint2*)dst)[off] = make_uint2(lo, hi);
  } else if (i < 2097152 + 1024) {
    int j = i - 2097152;
    if (j < 256)      ((float4*)biasq)[j]              = ((const float4*)qb)[j];
    else if (j < 512) ((float4*)(biasq + 1024))[j-256] = ((const float4*)kb)[j-256];
    else if (j < 768) ((float4*)(biasq + 2048))[j-512] = ((const float4*)vbs)[j-512];
    else              ((float4*)biaso)[j-768]          = ((const float4*)ob)[j-768];
  }
}

// ---------------- gemm1: QKV NT-GEMM, 256x256/BK=64, 8-phase counted-vmcnt --------
// Grid (16,12): 192 blocks, 1/CU. Per wave 128x64 output (M_rep=8, N_rep=4).
// Tile u staging (4 chunks, 2 gload16 each): chunk0 @ (u-2)ph3, chunks1-3 @
// (u-1)ph0/1/2. Buffer write-after-read separated by [lgkm0; barrier] (reads of
// buf[u&1] drain at (u-2)ph2). Tile-end wait: vmcnt(2) (one chunk in flight);
// vmcnt(0) only at t=14 (tail drain). Accumulation order identical to 2-phase
// version (ks0 then ks1 per tile) -> bit-identical numerics.
__global__ __launch_bounds__(512, 2) void gemm_qkv(
    const unsigned short* __restrict__ A, const unsigned short* __restrict__ B,
    const float* __restrict__ bias, unsigned short* __restrict__ dq,
    unsigned short* __restrict__ dk, unsigned short* __restrict__ vtout,
    const float* __restrict__ fc, const float* __restrict__ fs, int K) {
  __shared__ alignas(16) unsigned short sA[2][256 * 64];  // 64KB
  __shared__ alignas(16) unsigned short sB[2][256 * 64];  // 64KB
  const int tid = threadIdx.x;
  const int lane = tid & 63, wave = tid >> 6;
  const int ln = lane & 15, quad = lane >> 4;
  const int bm = blockIdx.x * 256, bn = blockIdx.y * 256;
  const int wr = (wave >> 2) * 128, wc = (wave & 3) * 64;
  const int NT = K >> 6;  // 16 K-tiles

  f32x4 acc[8][4];
#pragma unroll
  for (int i = 0; i < 8; ++i)
#pragma unroll
    for (int j = 0; j < 4; ++j) acc[i][j] = fzero4();

  // stage chunk ch (0..3) of K-tile tt into buf[tt&1]; source col pre-swizzled
#define STAGE(tt, ch) do {                                                   \
    int o_ = ((ch) * 512 + tid) * 8;                                         \
    int row_ = o_ >> 6, c_ = (o_ >> 3) & 7;                                  \
    int col_ = ((tt) << 6) + ((c_ ^ (row_ & 7)) << 3);                       \
    int bs_ = (tt) & 1;                                                      \
    gload16(A + (size_t)(bm + row_) * K + col_, (char*)sA[bs_] + o_ * 2);    \
    gload16(B + (size_t)(bn + row_) * K + col_, (char*)sB[bs_] + o_ * 2);    \
  } while (0)
#define BAR()   __builtin_amdgcn_s_barrier()
#define LGKM0() asm volatile("s_waitcnt lgkmcnt(0)" ::: "memory")

  // prologue: tile0 fully + tile1 chunk0; then wait vmcnt(2) (t1c0 may fly)
  STAGE(0, 0); STAGE(0, 1); STAGE(0, 2); STAGE(0, 3); STAGE(1, 0);
  asm volatile("s_waitcnt vmcnt(2)" ::: "memory");
  BAR();

#pragma unroll 2
  for (int t = 0; t < 16; ++t) {
    const unsigned short* cA = sA[t & 1];
    const unsigned short* cB = sB[t & 1];
    bf16x8 a0[4], a1[4], b0[4], b1[4];

    // ---- phase 0: read B ks0 + A ks0 i0-3 | stage t+1 c1 | MFMA ks0 i0-3
#pragma unroll
    for (int j = 0; j < 4; ++j) b0[j] = lds_swz(cB, wc + j * 16 + ln, quad);
#pragma unroll
    for (int i = 0; i < 4; ++i) a0[i] = lds_swz(cA, wr + i * 16 + ln, quad);
    if (t + 1 < NT) STAGE(t + 1, 1);
    BAR(); LGKM0();
    __builtin_amdgcn_s_setprio(1);
#pragma unroll
    for (int i = 0; i < 4; ++i)
#pragma unroll
      for (int j = 0; j < 4; ++j)
        acc[i][j] = __builtin_amdgcn_mfma_f32_16x16x32_bf16(a0[i], b0[j], acc[i][j], 0, 0, 0);
    __builtin_amdgcn_s_setprio(0);
    BAR();

    // ---- phase 1: read A ks0 i4-7 + B ks1 | stage t+1 c2 | MFMA ks0 i4-7
#pragma unroll
    for (int i = 0; i < 4; ++i) a1[i] = lds_swz(cA, wr + (i + 4) * 16 + ln, quad);
#pragma unroll
    for (int j = 0; j < 4; ++j) b1[j] = lds_swz(cB, wc + j * 16 + ln, 4 + quad);
    if (t + 1 < NT) STAGE(t + 1, 2);
    BAR(); LGKM0();
    __builtin_amdgcn_s_setprio(1);
#pragma unroll
    for (int i = 0; i < 4; ++i)
#pragma unroll
      for (int j = 0; j < 4; ++j)
        acc[i + 4][j] = __builtin_amdgcn_mfma_f32_16x16x32_bf16(a1[i], b0[j], acc[i + 4][j], 0, 0, 0);
    __builtin_amdgcn_s_setprio(0);
    BAR();

    // ---- phase 2: read A ks1 i0-7 | stage t+1 c3 | MFMA ks1 i0-3
#pragma unroll
    for (int i = 0; i < 4; ++i) a0[i] = lds_swz(cA, wr + i * 16 + ln, 4 + quad);
#pragma unroll
    for (int i = 0; i < 4; ++i) a1[i] = lds_swz(cA, wr + (i + 4) * 16 + ln, 4 + quad);
    if (t + 1 < NT) STAGE(t + 1, 3);
    BAR(); LGKM0();
    __builtin_amdgcn_s_setprio(1);
#pragma unroll
    for (int i = 0; i < 4; ++i)
#pragma unroll
      for (int j = 0; j < 4; ++j)
        acc[i][j] = __builtin_amdgcn_mfma_f32_16x16x32_bf16(a0[i], b1[j], acc[i][j], 0, 0, 0);
    __builtin_amdgcn_s_setprio(0);
    BAR();

    // ---- phase 3: stage t+2 c0 (current buf: reads drained at ph2) | MFMA ks1 i4-7
    if (t + 2 < NT) STAGE(t + 2, 0);
    BAR(); LGKM0();
    __builtin_amdgcn_s_setprio(1);
#pragma unroll
    for (int i = 0; i < 4; ++i)
#pragma unroll
      for (int j = 0; j < 4; ++j)
        acc[i + 4][j] = __builtin_amdgcn_mfma_f32_16x16x32_bf16(a1[i], b1[j], acc[i + 4][j], 0, 0, 0);
    __builtin_amdgcn_s_setprio(0);
    // tile-end: counted wait for next tile's data; one chunk (2 loads) may fly
    if (t < 14) {
      asm volatile("s_waitcnt vmcnt(2)" ::: "memory");
      BAR();
    } else if (t == 14) {
      asm volatile("s_waitcnt vmcnt(0)" ::: "memory");
      BAR();
    }
  }
#undef STAGE
#undef BAR
#undef LGKM0

  const int bufi = bn >> 10;                  // 0:q 1:k 2:v (block-uniform)
  const int hq = ((bn & 1023) + wc) >> 6;     // head, wave-uniform (wc mult of 64)
  if (bufi < 2) {
    // ---- q/k with fused RoPE ----
    unsigned short* const base = bufi == 0 ? dq : dk;
    const float qsc = bufi == 0 ? 0.180336880f : 1.0f;  // (1/8)*log2(e) for q
#pragma unroll
    for (int i = 0; i < 8; ++i)
#pragma unroll
      for (int j = 0; j < 4; ++j) {
        int n = bn + wc + j * 16 + ln;
        float bi = bias[n];
        int hd = j * 16 + ln;
        int pi = hd >> 1;
        bool evn = (ln & 1) == 0;
#pragma unroll
        for (int r = 0; r < 4; ++r) {
          int m = bm + wr + i * 16 + quad * 4 + r;
          float val = acc[i][j][r] + bi;
          float par = __shfl_xor(val, 1);
          float c = fc[m * 32 + pi], sn = fs[m * 32 + pi];
          float o = evn ? (val * c - par * sn) : (par * sn + val * c);
          base[((size_t)(hq * S_LEN + m)) * HD + hd] = f2b(o * qsc);
        }
      }
  } else {
    // ---- v: write transposed (h,hd,s) via per-wave LDS scratch [64 hd][128 s] ----
    __syncthreads();  // main-loop reads done; reuse sA/sB as 8x16KB scratch
    unsigned short* scr =
        (wave < 4 ? (unsigned short*)sA : (unsigned short*)sB) + (wave & 3) * 8192;
#pragma unroll
    for (int i = 0; i < 8; ++i)
#pragma unroll
      for (int j = 0; j < 4; ++j) {
        int n = bn + wc + j * 16 + ln;
        float bi = bias[n];
        int hd = j * 16 + ln;
#pragma unroll
        for (int r = 0; r < 4; ++r) {
          int sl = i * 16 + quad * 4 + r;                     // 0..127 (s-local)
          int byte = hd * 256 + ((((sl >> 3) ^ (hd & 7)) << 4)) + (sl & 7) * 2;
          *(unsigned short*)((char*)scr + byte) = f2b(acc[i][j][r] + bi);
        }
      }
    __syncthreads();
#pragma unroll
    for (int pass = 0; pass < 4; ++pass) {
      int row = pass * 16 + ln;  // hd
      uint4 d[4];
#pragma unroll
      for (int j = 0; j < 4; ++j) {
        int c = quad * 4 + j;  // 16B chunk = 8 s-elements
        d[j] = *(uint4*)((char*)scr + row * 256 + ((c ^ (row & 7)) << 4));
      }
      uint4* dst = (uint4*)(vtout + ((size_t)(hq * HD + row)) * S_LEN + bm + wr + quad * 32);
#pragma unroll
      for (int j = 0; j < 4; ++j) dst[j] = d[j];
    }
  }
}

// ---------------- gemm2: out-proj NT GEMM, 128x64 tile, f32 out -------------------
__global__ __launch_bounds__(256) void gemm_out(
    const unsigned short* __restrict__ A, const unsigned short* __restrict__ B,
    const float* __restrict__ bias, float* __restrict__ outF, int N, int K) {
  __shared__ alignas(16) unsigned short sA[2][128 * 32];
  __shared__ alignas(16) unsigned short sB[2][64 * 32];
  const int tid = threadIdx.x;
  const int lane = tid & 63, wave = tid >> 6;
  const int ln = lane & 15, quad = lane >> 4;
  const int bm = blockIdx.x * 128, bn = blockIdx.y * 64;
  const int wr = (wave >> 1) * 64, wc = (wave & 1) * 32;

  f32x4 acc[4][2];
#pragma unroll
  for (int i = 0; i < 4; ++i)
#pragma unroll
    for (int j = 0; j < 2; ++j) acc[i][j] = fzero4();

  {
#pragma unroll
    for (int i = 0; i < 2; ++i) {
      int o = (i * 256 + tid) * 16;
      int e = o >> 1;
      int row = e >> 5, col = e & 31;
      gload16(A + (size_t)(bm + row) * K + col, (char*)sA[0] + o);
    }
    int o = tid * 16;
    int e = o >> 1;
    int row = e >> 5, col = e & 31;
    gload16(B + (size_t)(bn + row) * K + col, (char*)sB[0] + o);
  }

  int buf = 0;
  for (int k0 = 0; k0 < K; k0 += 32, buf ^= 1) {
    __syncthreads();
    if (k0 + 32 < K) {
#pragma unroll
      for (int i = 0; i < 2; ++i) {
        int o = (i * 256 + tid) * 16;
        int e = o >> 1;
        int row = e >> 5, col = e & 31;
        gload16(A + (size_t)(bm + row) * K + k0 + 32 + col, (char*)sA[buf ^ 1] + o);
      }
      int o = tid * 16;
      int e = o >> 1;
      int row = e >> 5, col = e & 31;
      gload16(B + (size_t)(bn + row) * K + k0 + 32 + col, (char*)sB[buf ^ 1] + o);
    }
    bf16x8 af[4], bfr[2];
#pragma unroll
    for (int i = 0; i < 4; ++i)
      af[i] = *(const bf16x8*)&sA[buf][(wr + i * 16 + ln) * 32 + quad * 8];
#pragma unroll
    for (int j = 0; j < 2; ++j)
      bfr[j] = *(const bf16x8*)&sB[buf][(wc + j * 16 + ln) * 32 + quad * 8];
#pragma unroll
    for (int i = 0; i < 4; ++i)
#pragma unroll
      for (int j = 0; j < 2; ++j)
        acc[i][j] = __builtin_amdgcn_mfma_f32_16x16x32_bf16(af[i], bfr[j], acc[i][j], 0, 0, 0);
  }

#pragma unroll
  for (int i = 0; i < 4; ++i)
#pragma unroll
    for (int j = 0; j < 2; ++j) {
      int n = bn + wc + j * 16 + ln;
      float bi = bias[n];
#pragma unroll
      for (int r = 0; r < 4; ++r) {
        int m = bm + wr + i * 16 + quad * 4 + r;
        outF[(size_t)m * N + n] = acc[i][j][r] + bi;
      }
    }
}

// ---------------- Flash attention, causal, exp2 softmax (no running max) ----------
// 1024 blocks x 512 threads. Block c: head h=c&15 (2 heads/XCD -> KV L2-resident),
// q-tile qt=63-(c>>4) (heavy first). Wave-group 0 computes EVEN kv tiles, group 1
// ODD kv tiles -> every wave active every staged step. exp2-no-max makes partial
// (O,l) summable: one LDS merge at the end. P fully in-register via swapped QK^T
// (mfma(K,Q)) + pk2t + permlane32/16_swap. 4 staging buffers = 64KB LDS.
__global__ __launch_bounds__(512, 4) void flash_kernel(
    const unsigned short* __restrict__ qg, const unsigned short* __restrict__ kg,
    const unsigned short* __restrict__ vtg, unsigned short* __restrict__ attn) {
  __shared__ alignas(16) unsigned short sK[2][2][64 * 64];  // [buf][tile-parity]
  __shared__ alignas(16) unsigned short sV[2][2][64 * 64];

  const int tid = threadIdx.x;
  const int lane = tid & 63, wave = tid >> 6;
  const int w = wave & 3, grp = wave >> 2;   // grp 0: even kv tiles, 1: odd
  const int ln = lane & 15, quad = lane >> 4;
  const int c = blockIdx.x;
  const int h = c & 15;
  const int qt = 63 - (c >> 4);              // q-tile index, big blocks first
  const int qrow = qt * 64 + w * 16;

  const unsigned short* qh = qg + (size_t)h * (S_LEN * HD);
  const unsigned short* kh = kg + (size_t)h * (S_LEN * HD);
  const unsigned short* vh = vtg + (size_t)h * (HD * S_LEN);

  bf16x8 qf[2];
  qf[0] = *(const bf16x8*)(qh + (size_t)(qrow + ln) * HD + quad * 8);
  qf[1] = *(const bf16x8*)(qh + (size_t)(qrow + ln) * HD + 32 + quad * 8);

  f32x4 o_acc[4];
  f32x4 l_acc = fzero4();
#pragma unroll
  for (int t = 0; t < 4; ++t) o_acc[t] = fzero4();
  bf16x8 ones;
#pragma unroll
  for (int j = 0; j < 8; ++j) ones[j] = (short)0x3F80;  // bf16 1.0

  const int nst = (qt + 2) >> 1;             // ceil((qt+1)/2) staged steps
  const int srow = tid >> 3, sch = tid & 7;  // 512 threads: 64 rows x 8 chunks
  const int kswz = (sch ^ (srow & 7)) << 3;  // elem offset, matches lds_swz reads

  // preload step 0: tiles 0 (->[0][0]) and 1 (->[0][1]); tile 1 always in-bounds
  gload16(kh + (size_t)srow * HD + kswz, (char*)sK[0][0] + tid * 16);
  gload16(kh + (size_t)(64 + srow) * HD + kswz, (char*)sK[0][1] + tid * 16);
  gload16(vh + (size_t)srow * S_LEN + kswz, (char*)sV[0][0] + tid * 16);
  gload16(vh + (size_t)srow * S_LEN + 64 + kswz, (char*)sV[0][1] + tid * 16);

  int buf = 0;
  for (int s = 0; s < nst; ++s, buf ^= 1) {
    __syncthreads();  // drains DMA for buf; guards buf^1 (read two steps ago)
    if (s + 1 < nst) {
      const int kvE = (2 * s + 2) * 64, kvO = kvE + 64;  // kvO <= 4032 always
      gload16(kh + (size_t)(kvE + srow) * HD + kswz, (char*)sK[buf ^ 1][0] + tid * 16);
      gload16(kh + (size_t)(kvO + srow) * HD + kswz, (char*)sK[buf ^ 1][1] + tid * 16);
      gload16(vh + (size_t)srow * S_LEN + kvE + kswz, (char*)sV[buf ^ 1][0] + tid * 16);
      gload16(vh + (size_t)srow * S_LEN + kvO + kswz, (char*)sV[buf ^ 1][1] + tid * 16);
    }
    const int kt = 2 * s + grp;
    if (kt > qt) continue;  // group-1 tail when qt even (barrier already done)
    const unsigned short* kp = sK[buf][grp];
    const unsigned short* vp = sV[buf][grp];

    // S^T = K Q^T: sc[t] holds rows kv-local 16t+quad*4+r, col q-local ln
    f32x4 sc[4];
#pragma unroll
    for (int t = 0; t < 4; ++t) sc[t] = fzero4();
#pragma unroll
    for (int t = 0; t < 4; ++t) {
      bf16x8 kb0 = lds_swz(kp, t * 16 + ln, quad);
      bf16x8 kb1 = lds_swz(kp, t * 16 + ln, 4 + quad);
      sc[t] = __builtin_amdgcn_mfma_f32_16x16x32_bf16(kb0, qf[0], sc[t], 0, 0, 0);
      sc[t] = __builtin_amdgcn_mfma_f32_16x16x32_bf16(kb1, qf[1], sc[t], 0, 0, 0);
    }

    // p = exp2(s); mask only on the diagonal tile (kt == qt)
    float e[4][4];
    if (kt == qt) {
#pragma unroll
      for (int t = 0; t < 4; ++t)
#pragma unroll
        for (int r = 0; r < 4; ++r) {
          int kvl = 16 * t + quad * 4 + r;
          e[t][r] = (kvl <= w * 16 + ln) ? __builtin_amdgcn_exp2f(sc[t][r]) : 0.0f;
        }
    } else {
#pragma unroll
      for (int t = 0; t < 4; ++t)
#pragma unroll
        for (int r = 0; r < 4; ++r) e[t][r] = __builtin_amdgcn_exp2f(sc[t][r]);
    }

    // In-register P -> A-fragment: lane(ln,quad) needs P[q=ln][kv=8*quad+0..7]
    // (pa0) and [32+8*quad+0..7] (pa1). permlane32_swap then permlane16_swap
    // gathers exactly (t=quad>>1, q'=2(quad&1)+{0,1}).
    unsigned int x0 = pk2t(e[0][0], e[0][1]), x1 = pk2t(e[0][2], e[0][3]);
    unsigned int y0 = pk2t(e[1][0], e[1][1]), y1 = pk2t(e[1][2], e[1][3]);
    unsigned int z0 = pk2t(e[2][0], e[2][1]), z1 = pk2t(e[2][2], e[2][3]);
    unsigned int w0 = pk2t(e[3][0], e[3][1]), w1 = pk2t(e[3][2], e[3][3]);
    auto a32 = __builtin_amdgcn_permlane32_swap(x0, y0, false, false);
    auto a16 = __builtin_amdgcn_permlane16_swap(a32[0], a32[1], false, false);
    auto b32 = __builtin_amdgcn_permlane32_swap(x1, y1, false, false);
    auto b16 = __builtin_amdgcn_permlane16_swap(b32[0], b32[1], false, false);
    auto c32 = __builtin_amdgcn_permlane32_swap(z0, w0, false, false);
    auto c16 = __builtin_amdgcn_permlane16_swap(c32[0], c32[1], false, false);
    auto d32 = __builtin_amdgcn_permlane32_swap(z1, w1, false, false);
    auto d16 = __builtin_amdgcn_permlane16_swap(d32[0], d32[1], false, false);
    union { uint4 u; bf16x8 b; } pa0u, pa1u;
    pa0u.u = make_uint4(a16[0], b16[0], a16[1], b16[1]);
    pa1u.u = make_uint4(c16[0], d16[0], c16[1], d16[1]);
    const bf16x8 pa0 = pa0u.b, pa1 = pa1u.b;

    // l += P @ ones
    l_acc = __builtin_amdgcn_mfma_f32_16x16x32_bf16(pa0, ones, l_acc, 0, 0, 0);
    l_acc = __builtin_amdgcn_mfma_f32_16x16x32_bf16(pa1, ones, l_acc, 0, 0, 0);

    // O += P @ V
#pragma unroll
    for (int t = 0; t < 4; ++t) {
      bf16x8 vb0 = lds_swz(vp, t * 16 + ln, quad);
      bf16x8 vb1 = lds_swz(vp, t * 16 + ln, 4 + quad);
      o_acc[t] = __builtin_amdgcn_mfma_f32_16x16x32_bf16(pa0, vb0, o_acc[t], 0, 0, 0);
      o_acc[t] = __builtin_amdgcn_mfma_f32_16x16x32_bf16(pa1, vb1, o_acc[t], 0, 0, 0);
    }
  }

  // merge group 1's partial (O,l) into group 0 via LDS (reuse sK), then epilogue
  __syncthreads();  // all compute done; no DMA in flight
  float* mrg = (float*)sK;
  const int mi = (w * 64 + lane) * 20;  // 20 f32/lane, 16B-aligned blob
  if (grp == 1) {
    *(f32x4*)&mrg[mi +  0] = o_acc[0];
    *(f32x4*)&mrg[mi +  4] = o_acc[1];
    *(f32x4*)&mrg[mi +  8] = o_acc[2];
    *(f32x4*)&mrg[mi + 12] = o_acc[3];
    *(f32x4*)&mrg[mi + 16] = l_acc;
  }
  __syncthreads();
  if (grp == 0) {
    o_acc[0] += *(const f32x4*)&mrg[mi + 0];
    o_acc[1] += *(const f32x4*)&mrg[mi + 4];
    o_acc[2] += *(const f32x4*)&mrg[mi + 8];
    o_acc[3] += *(const f32x4*)&mrg[mi + 12];
    l_acc += *(const f32x4*)&mrg[mi + 16];
    float inv[4];
#pragma unroll
    for (int r = 0; r < 4; ++r) inv[r] = 1.0f / l_acc[r];
#pragma unroll
    for (int t = 0; t < 4; ++t)
#pragma unroll
      for (int r = 0; r < 4; ++r) {
        int row = qrow + quad * 4 + r;
        attn[(size_t)row * DIM + h * HD + t * 16 + ln] = f2b(o_acc[t][r] * inv[r]);
      }
  }
}

extern "C" void kernel_launch(void* const* d_in, const int* in_sizes, int n_in,
                              void* d_out, int out_size, void* d_ws, size_t ws_size,
                              hipStream_t stream) {
  const float* x    = (const float*)d_in[0];
  const float* fc   = (const float*)d_in[2];
  const float* fs   = (const float*)d_in[3];
  const float* wqw  = (const float*)d_in[5];
  const float* wqb  = (const float*)d_in[6];
  const float* wkw  = (const float*)d_in[7];
  const float* wkb  = (const float*)d_in[8];
  const float* wvw  = (const float*)d_in[9];
  const float* wvb  = (const float*)d_in[10];
  const float* wow  = (const float*)d_in[11];
  const float* wobf = (const float*)d_in[12];
  float* out = (float*)d_out;

  char* ws = (char*)d_ws;
  const size_t MB = (size_t)1 << 20;
  unsigned short* xb    = (unsigned short*)(ws + 0);
  unsigned short* wqkvb = (unsigned short*)(ws + 8 * MB);
  unsigned short* wobb  = (unsigned short*)(ws + 16 * MB);
  float* biasq = (float*)(ws + 18 * MB);
  float* biaso = (float*)(ws + 18 * MB + 65536);
  unsigned short* qb_ = (unsigned short*)(ws + 19 * MB);
  unsigned short* kb_ = (unsigned short*)(ws + 27 * MB);
  unsigned short* vt  = (unsigned short*)(ws + 35 * MB);  // vT written by gemm1
  unsigned short* attn = (unsigned short*)(ws + 0);       // aliases xb (dead after gemm1)

  cvt_all<<<8196, 256, 0, stream>>>(x, wqw, wkw, wvw, wow, wqb, wkb, wvb, wobf,
                                    xb, wqkvb, wobb, biasq, biaso);
  gemm_qkv<<<dim3(16, 12), 512, 0, stream>>>(xb, wqkvb, biasq, qb_, kb_, vt, fc, fs, 1024);
  flash_kernel<<<1024, 512, 0, stream>>>(qb_, kb_, vt, attn);
  gemm_out<<<dim3(32, 16), 256, 0, stream>>>(attn, wobb, biaso, out, 1024, 1024);
}